// Round 12
// baseline (4994.197 us; speedup 1.0000x reference)
//
#include <hip/hip_runtime.h>
#include <hip/hip_bf16.h>
#include <cstdint>
#include <cstddef>

#define B_   64
#define T_   512
#define D_   512
#define H0_  1024
#define H1_  512
#define NWORK 256    // 2 groups x 128 blocks, 1 block/CU, plain launch

typedef __attribute__((ext_vector_type(8))) short bf16x8;
typedef __attribute__((ext_vector_type(4))) float f32x4;
typedef unsigned long long u64;

// LDS: U0 64KB @0 | W1 32KB @65536 | zp0 18,432B @98304 | zp1 10,240B @116736
#define LDS_U0  0
#define LDS_W1  65536
#define LDS_ZP0 98304
#define LDS_ZP1 116736
#define LDS_BYTES 126976
#define ZROW0 36
#define ZROW1 20

__device__ __forceinline__ float sigmf(float x) { return 1.0f / (1.0f + __expf(-x)); }
__device__ __forceinline__ unsigned short bf16bits(float x) {
    union { __hip_bfloat16 h; unsigned short s; } u; u.h = __float2bfloat16(x); return u.s;
}
__device__ __forceinline__ u64 ald(const void* p) {
    return __hip_atomic_load((const u64*)p, __ATOMIC_RELAXED, __HIP_MEMORY_SCOPE_AGENT);
}

// ---------------------------------------------------------------------------
__global__ void mask_kernel(const float* __restrict__ x, unsigned char* __restrict__ mask) {
    int row  = blockIdx.x * 4 + (threadIdx.x >> 6);
    int lane = threadIdx.x & 63;
    const float4* p = reinterpret_cast<const float4*>(x + (size_t)row * D_) + lane * 2;
    float4 a = p[0], b = p[1];
    bool nz = (a.x != 0.f) | (a.y != 0.f) | (a.z != 0.f) | (a.w != 0.f)
            | (b.x != 0.f) | (b.y != 0.f) | (b.z != 0.f) | (b.w != 0.f);
    int m = __any(nz);
    if (lane == 0) mask[row] = m ? 1 : 0;
}

__global__ void xbf_kernel(const float* __restrict__ in, __hip_bfloat16* __restrict__ xbf) {
    int i  = blockIdx.x * 256 + threadIdx.x;
    int d8 = i & 63;
    int row = i >> 6;
    int b = row >> 9, t = row & 511;
    const float* src = in + (size_t)row * D_ + d8 * 8;
    __hip_bfloat16 o[8];
    #pragma unroll
    for (int j = 0; j < 8; ++j) o[j] = __float2bfloat16(src[j]);
    *reinterpret_cast<bf16x8*>(xbf + ((size_t)t * B_ + b) * D_ + d8 * 8) =
        *reinterpret_cast<bf16x8*>(o);
}

// ---------------------------------------------------------------------------
// Fused persistent kernel, 2 independent batch-group chains, per-WAVE flags.
// Group g = bid>>7 owns batches [g*32, g*32+32); block lb = bid&127 owns
// 8 L0-units + 4 L1-units. Phase p: PRE = x_p*W0 (reg frags) + mask prefetch;
// all-wave poll(512 wave-flags >= p); prefetch ALL h1+h0 chunks (48 u64);
// h1 -> U1 (z1); h0 -> U0 (z0) + W1 (z1); dumps -> 1 sync -> gates ->
// h stores -> per-wave vmcnt(0) + flag -> out store (off critical path).
// All recurrent traffic agent-scope relaxed (sc0sc1, LLC-direct); no fences.
// ---------------------------------------------------------------------------
__global__ __launch_bounds__(256, 1)
void lstm_persistent(const __hip_bfloat16* __restrict__ xbf,
    const float* __restrict__ W0, const float* __restrict__ U0,
    const float* __restrict__ W1, const float* __restrict__ U1,
    const float* __restrict__ b0, const float* __restrict__ b1,
    const unsigned char* __restrict__ mask,
    __hip_bfloat16* h0ring, __hip_bfloat16* h1ring, float* __restrict__ out,
    int* flags)
{
    __shared__ __align__(16) unsigned char smem[LDS_BYTES];
    const int bid = blockIdx.x;
    const int g   = bid >> 7;          // batch group (0/1)
    const int lb  = bid & 127;         // block within group
    const int tid = threadIdx.x;
    const int w = tid >> 6, lane = tid & 63;
    const int mr = lane & 15, kgrp = lane >> 4;
    const int ub0 = lb * 8, ub1 = lb * 4;
    const int brow = g * 32;           // batch row base
    int* gflags = flags + g * 512;     // 512 wave-flags per group

    __hip_bfloat16* lu0h = (__hip_bfloat16*)(smem + LDS_U0);
    __hip_bfloat16* lw1h = (__hip_bfloat16*)(smem + LDS_W1);

    // ---- one-time LDS fill: U0 frags (cid 0..31, nf 0..1)
    for (int e = tid; e < 32 * 2 * 64; e += 256) {
        int ln  = e & 63;
        int nf  = (e >> 6) & 1;
        int cid = e >> 7;
        int nn  = nf * 16 + (ln & 15);
        int col = (nn >> 3) * 1024 + ub0 + (nn & 7);
        int kb  = cid * 32 + (ln >> 4) * 8;
        __hip_bfloat16* dst = lu0h + (size_t)e * 8;
        #pragma unroll
        for (int j = 0; j < 8; ++j)
            dst[j] = __float2bfloat16(U0[(size_t)(kb + j) * 4096 + col]);
    }
    // ---- one-time LDS fill: W1 frags (cid 0..31)
    for (int e = tid; e < 32 * 64; e += 256) {
        int ln  = e & 63;
        int cid = e >> 6;
        int nn  = ln & 15;
        int col = (nn >> 2) * 512 + ub1 + (nn & 3);
        int kb  = cid * 32 + (ln >> 4) * 8;
        __hip_bfloat16* dst = lw1h + (size_t)e * 8;
        #pragma unroll
        for (int j = 0; j < 8; ++j)
            dst[j] = __float2bfloat16(W1[(size_t)(kb + j) * 2048 + col]);
    }
    // ---- register frags: W0 (PRE) and U1, loop-invariant
    bf16x8 bw0[4][2];
    {
        int nn0 = lane & 15;
        #pragma unroll
        for (int c = 0; c < 4; ++c)
            #pragma unroll
            for (int nf = 0; nf < 2; ++nf) {
                int nn  = nf * 16 + nn0;
                int col = (nn >> 3) * 1024 + ub0 + (nn & 7);
                int kb  = (w * 4 + c) * 32 + kgrp * 8;
                union { short s[8]; bf16x8 v; } t;
                #pragma unroll
                for (int j = 0; j < 8; ++j)
                    t.s[j] = (short)bf16bits(W0[(size_t)(kb + j) * 4096 + col]);
                bw0[c][nf] = t.v;
            }
    }
    bf16x8 bu1[4];
    {
        int nn  = lane & 15;
        int col = (nn >> 2) * 512 + ub1 + (nn & 3);
        #pragma unroll
        for (int c = 0; c < 4; ++c) {
            int kb  = (w * 4 + c) * 32 + kgrp * 8;
            union { short s[8]; bf16x8 v; } t;
            #pragma unroll
            for (int j = 0; j < 8; ++j)
                t.s[j] = (short)bf16bits(U1[(size_t)(kb + j) * 2048 + col]);
            bu1[c] = t.v;
        }
    }

    // ---- per-thread gate state: bl = tid>>3 (32 batches), qp = tid&7
    const int bl = tid >> 3;
    const int qp = tid & 7;
    float h0reg[2] = {0.f, 0.f}, c0reg[2] = {0.f, 0.f}, br0[8];
    float h1reg[2] = {0.f, 0.f}, c1reg[2] = {0.f, 0.f}, br1[8];
    if (qp < 4) {
        #pragma unroll
        for (int i = 0; i < 2; ++i)
            #pragma unroll
            for (int gg = 0; gg < 4; ++gg)
                br0[i * 4 + gg] = b0[gg * H0_ + ub0 + qp * 2 + i];
    }
    if (qp < 2) {
        #pragma unroll
        for (int i = 0; i < 2; ++i)
            #pragma unroll
            for (int gg = 0; gg < 4; ++gg)
                br1[i * 4 + gg] = b1[gg * H1_ + ub1 + qp * 2 + i];
    }
    __syncthreads();

    float* zp0 = (float*)(smem + LDS_ZP0);
    float* zp1 = (float*)(smem + LDS_ZP1);
    const bf16x8* lu0 = (const bf16x8*)(smem + LDS_U0);
    const bf16x8* lw1 = (const bf16x8*)(smem + LDS_W1);

    #pragma unroll 1
    for (int p = 0; p <= T_; ++p) {
        const bool doL0 = (p < T_);
        const bool doL1 = (p >= 1);

        f32x4 acc0[2][2];
        f32x4 acc1[2];
        #pragma unroll
        for (int m = 0; m < 2; ++m) {
            f32x4 z = {0.f, 0.f, 0.f, 0.f};
            acc0[m][0] = z; acc0[m][1] = z; acc1[m] = z;
        }

        // ---- PRE: mask prefetch + z0 x-part (W0 reg frags; pre-poll)
        bool msk0 = false, msk1 = false;
        if (doL0) msk0 = mask[(brow + bl) * T_ + p] != 0;
        if (doL1) msk1 = mask[(brow + bl) * T_ + (p - 1)] != 0;
        if (doL0) {
            const __hip_bfloat16* xa = xbf + (size_t)p * (B_ * D_);
            #pragma unroll
            for (int c = 0; c < 4; ++c) {
                const int cid = w * 4 + c;
                #pragma unroll
                for (int m = 0; m < 2; ++m) {
                    bf16x8 af = *(const bf16x8*)(xa + (size_t)(brow + m * 16 + mr) * D_ + cid * 32 + kgrp * 8);
                    acc0[m][0] = __builtin_amdgcn_mfma_f32_16x16x32_bf16(af, bw0[c][0], acc0[m][0], 0, 0, 0);
                    acc0[m][1] = __builtin_amdgcn_mfma_f32_16x16x32_bf16(af, bw0[c][1], acc0[m][1], 0, 0, 0);
                }
            }
        }

        // ---- wait: ALL waves poll own group's 512 wave-flags >= p (no barrier)
        if (p > 0) {
            const u64* f = (const u64*)gflags + lane;
            for (;;) {
                u64 a = ald(f);
                u64 b = ald(f + 64);
                u64 c = ald(f + 128);
                u64 d = ald(f + 192);
                bool ok = ((int)a >= p) && ((int)(a >> 32) >= p)
                       && ((int)b >= p) && ((int)(b >> 32) >= p)
                       && ((int)c >= p) && ((int)(c >> 32) >= p)
                       && ((int)d >= p) && ((int)(d >> 32) >= p);
                if (__all(ok)) break;
                __builtin_amdgcn_s_sleep(1);
            }
        }

        const __hip_bfloat16* h0r = h0ring + (size_t)((p + 1) & 1) * (B_ * H0_); // h0(p-1)
        const __hip_bfloat16* h1r = h1ring + (size_t)(p & 1) * (B_ * H1_);       // h1(p-2)

        // ---- prefetch ALL h1 + h0 chunks upfront (48 u64 in flight)
        u64 h1a[4][4];
        if (doL1) {
            #pragma unroll
            for (int c = 0; c < 4; ++c) {
                const __hip_bfloat16* src = h1r + w * 128 + c * 32 + kgrp * 8;
                #pragma unroll
                for (int m = 0; m < 2; ++m) {
                    const u64* hp = (const u64*)(src + (size_t)(brow + m * 16 + mr) * H1_);
                    h1a[c][2 * m]     = ald(hp);
                    h1a[c][2 * m + 1] = ald(hp + 1);
                }
            }
        }
        u64 h0a[8][4];
        #pragma unroll
        for (int c = 0; c < 8; ++c) {
            const __hip_bfloat16* src = h0r + w * 256 + c * 32 + kgrp * 8;
            #pragma unroll
            for (int m = 0; m < 2; ++m) {
                const u64* hp = (const u64*)(src + (size_t)(brow + m * 16 + mr) * H0_);
                h0a[c][2 * m]     = ald(hp);
                h0a[c][2 * m + 1] = ald(hp + 1);
            }
        }

        // ---- consume h1 (U1 reg frags -> z1)
        if (doL1) {
            #pragma unroll
            for (int c = 0; c < 4; ++c) {
                #pragma unroll
                for (int m = 0; m < 2; ++m) {
                    union { u64 u[2]; bf16x8 v; } au;
                    au.u[0] = h1a[c][2 * m]; au.u[1] = h1a[c][2 * m + 1];
                    acc1[m] = __builtin_amdgcn_mfma_f32_16x16x32_bf16(au.v, bu1[c], acc1[m], 0, 0, 0);
                }
            }
        }

        // ---- consume h0: shared A-frags feed U0 (z0) and W1 (z1)
        #pragma unroll
        for (int c = 0; c < 8; ++c) {
            const int wc = w * 8 + c;
            bf16x8 bu0a = lu0[(wc * 2 + 0) * 64 + lane];
            bf16x8 bu0b = lu0[(wc * 2 + 1) * 64 + lane];
            bf16x8 bw1  = lw1[wc * 64 + lane];
            #pragma unroll
            for (int m = 0; m < 2; ++m) {
                union { u64 u[2]; bf16x8 v; } au;
                au.u[0] = h0a[c][2 * m]; au.u[1] = h0a[c][2 * m + 1];
                if (doL0) {
                    acc0[m][0] = __builtin_amdgcn_mfma_f32_16x16x32_bf16(au.v, bu0a, acc0[m][0], 0, 0, 0);
                    acc0[m][1] = __builtin_amdgcn_mfma_f32_16x16x32_bf16(au.v, bu0b, acc0[m][1], 0, 0, 0);
                }
                if (doL1)
                    acc1[m] = __builtin_amdgcn_mfma_f32_16x16x32_bf16(au.v, bw1, acc1[m], 0, 0, 0);
            }
        }

        // ---- dumps to disjoint LDS, ONE sync
        if (doL0) {
            #pragma unroll
            for (int m = 0; m < 2; ++m)
                #pragma unroll
                for (int nf = 0; nf < 2; ++nf)
                    #pragma unroll
                    for (int r = 0; r < 4; ++r)
                        zp0[(w * 32 + m * 16 + kgrp * 4 + r) * ZROW0 + nf * 16 + mr] =
                            acc0[m][nf][r];
        }
        if (doL1) {
            #pragma unroll
            for (int m = 0; m < 2; ++m)
                #pragma unroll
                for (int r = 0; r < 4; ++r)
                    zp1[(w * 32 + m * 16 + kgrp * 4 + r) * ZROW1 + mr] = acc1[m][r];
        }
        __syncthreads();

        // ---- gates0 (qp<4) and gates1 (qp<2), then h stores
        if (doL0 && qp < 4) {
            #pragma unroll
            for (int i = 0; i < 2; ++i) {
                const int ul = qp * 2 + i;
                float z[4];
                #pragma unroll
                for (int gg = 0; gg < 4; ++gg) {
                    float s = br0[i * 4 + gg];
                    #pragma unroll
                    for (int wv = 0; wv < 4; ++wv)
                        s += zp0[(wv * 32 + bl) * ZROW0 + gg * 8 + ul];
                    z[gg] = s;
                }
                float ig = sigmf(z[0]), fg = sigmf(z[1]);
                float gv = tanhf(z[2]), og = sigmf(z[3]);
                float cn = fg * c0reg[i] + ig * gv;
                float hn = og * tanhf(cn);
                if (msk0) { c0reg[i] = cn; h0reg[i] = hn; }
            }
            __hip_bfloat16* h0w = h0ring + (size_t)(p & 1) * (B_ * H0_);
            union { unsigned short s[2]; unsigned u; } hv;
            hv.s[0] = bf16bits(h0reg[0]);
            hv.s[1] = bf16bits(h0reg[1]);
            __hip_atomic_store((unsigned*)&h0w[(size_t)(brow + bl) * H0_ + ub0 + qp * 2], hv.u,
                               __ATOMIC_RELAXED, __HIP_MEMORY_SCOPE_AGENT);
        }
        if (doL1 && qp < 2) {
            #pragma unroll
            for (int i = 0; i < 2; ++i) {
                const int ul = qp * 2 + i;
                float z[4];
                #pragma unroll
                for (int gg = 0; gg < 4; ++gg) {
                    float s = br1[i * 4 + gg];
                    #pragma unroll
                    for (int wv = 0; wv < 4; ++wv)
                        s += zp1[(wv * 32 + bl) * ZROW1 + gg * 4 + ul];
                    z[gg] = s;
                }
                float ig = sigmf(z[0]), fg = sigmf(z[1]);
                float gv = tanhf(z[2]), og = sigmf(z[3]);
                float cn = fg * c1reg[i] + ig * gv;
                float hn = og * tanhf(cn);
                if (msk1) { c1reg[i] = cn; h1reg[i] = hn; }
            }
            __hip_bfloat16* h1w = h1ring + (size_t)((p + 1) & 1) * (B_ * H1_); // slot (p-1)&1
            union { unsigned short s[2]; unsigned u; } hv;
            hv.s[0] = bf16bits(h1reg[0]);
            hv.s[1] = bf16bits(h1reg[1]);
            __hip_atomic_store((unsigned*)&h1w[(size_t)(brow + bl) * H1_ + ub1 + qp * 2], hv.u,
                               __ATOMIC_RELAXED, __HIP_MEMORY_SCOPE_AGENT);
        }

        // ---- per-wave arrive: drain own stores, publish own wave flag
        if (p < T_) {
            asm volatile("s_waitcnt vmcnt(0)" ::: "memory");
            if (lane == 0)
                __hip_atomic_store(gflags + lb * 4 + w, p + 1,
                                   __ATOMIC_RELAXED, __HIP_MEMORY_SCOPE_AGENT);
        }

        // ---- out store AFTER flag publish (nobody reads out)
        if (doL1 && qp < 2) {
            const int t1 = p - 1;
            float2 ov; ov.x = h1reg[0]; ov.y = h1reg[1];
            *reinterpret_cast<float2*>(&out[((size_t)(brow + bl) * T_ + t1) * H1_ + ub1 + qp * 2]) = ov;
        }
    }
}

// ---------------------------------------------------------------------------
extern "C" void kernel_launch(void* const* d_in, const int* in_sizes, int n_in,
                              void* d_out, int out_size, void* d_ws, size_t ws_size,
                              hipStream_t stream)
{
    const float* inputs = (const float*)d_in[0];
    const float* W0     = (const float*)d_in[1];
    const float* U0     = (const float*)d_in[2];
    const float* b0     = (const float*)d_in[3];
    const float* W1     = (const float*)d_in[4];
    const float* U1     = (const float*)d_in[5];
    const float* b1     = (const float*)d_in[6];
    float* out = (float*)d_out;

    // ws (bf16 elems): xbf 16,777,216 | h0ring 131,072 | h1ring 65,536
    //                  | mask 32,768 B | flags 4,096 B  (~32.4 MiB)
    __hip_bfloat16* xbf    = (__hip_bfloat16*)d_ws;
    __hip_bfloat16* h0ring = xbf + 16777216;
    __hip_bfloat16* h1ring = h0ring + 131072;
    unsigned char*  mask   = (unsigned char*)(h1ring + 65536);
    int* flags = (int*)(mask + 32768);

    hipMemsetAsync(h0ring, 0, (131072 + 65536) * sizeof(__hip_bfloat16), stream);
    hipMemsetAsync(flags, 0, 1024 * sizeof(int), stream);
    mask_kernel<<<(B_ * T_) / 4, 256, 0, stream>>>(inputs, mask);
    xbf_kernel<<<(B_ * T_ * D_ / 8) / 256, 256, 0, stream>>>(inputs, xbf);

    lstm_persistent<<<dim3(NWORK), dim3(256), 0, stream>>>(
        xbf, W0, U0, W1, U1, b0, b1, mask, h0ring, h1ring, out, flags);
}

// Round 13
// 4891.205 us; speedup vs baseline: 1.0211x; 1.0211x over previous
//
#include <hip/hip_runtime.h>
#include <hip/hip_bf16.h>
#include <cstdint>
#include <cstddef>

#define B_   64
#define T_   512
#define D_   512
#define H0_  1024
#define H1_  512
#define NWORK 256    // 2 groups x 128 blocks, 1 block/CU, plain launch

typedef __attribute__((ext_vector_type(8))) short bf16x8;
typedef __attribute__((ext_vector_type(4))) float f32x4;
typedef unsigned long long u64;

// LDS: U0 64KB @0 | W1 32KB @65536 | zp0 18,432B @98304 | zp1 10,240B @116736
#define LDS_U0  0
#define LDS_W1  65536
#define LDS_ZP0 98304
#define LDS_ZP1 116736
#define LDS_BYTES 126976
#define ZROW0 36
#define ZROW1 20

__device__ __forceinline__ float sigmf(float x) { return 1.0f / (1.0f + __expf(-x)); }
__device__ __forceinline__ unsigned short bf16bits(float x) {
    union { __hip_bfloat16 h; unsigned short s; } u; u.h = __float2bfloat16(x); return u.s;
}
__device__ __forceinline__ u64 ald(const void* p) {
    return __hip_atomic_load((const u64*)p, __ATOMIC_RELAXED, __HIP_MEMORY_SCOPE_AGENT);
}

// ---------------------------------------------------------------------------
__global__ void mask_kernel(const float* __restrict__ x, unsigned char* __restrict__ mask) {
    int row  = blockIdx.x * 4 + (threadIdx.x >> 6);
    int lane = threadIdx.x & 63;
    const float4* p = reinterpret_cast<const float4*>(x + (size_t)row * D_) + lane * 2;
    float4 a = p[0], b = p[1];
    bool nz = (a.x != 0.f) | (a.y != 0.f) | (a.z != 0.f) | (a.w != 0.f)
            | (b.x != 0.f) | (b.y != 0.f) | (b.z != 0.f) | (b.w != 0.f);
    int m = __any(nz);
    if (lane == 0) mask[row] = m ? 1 : 0;
}

__global__ void xbf_kernel(const float* __restrict__ in, __hip_bfloat16* __restrict__ xbf) {
    int i  = blockIdx.x * 256 + threadIdx.x;
    int d8 = i & 63;
    int row = i >> 6;
    int b = row >> 9, t = row & 511;
    const float* src = in + (size_t)row * D_ + d8 * 8;
    __hip_bfloat16 o[8];
    #pragma unroll
    for (int j = 0; j < 8; ++j) o[j] = __float2bfloat16(src[j]);
    *reinterpret_cast<bf16x8*>(xbf + ((size_t)t * B_ + b) * D_ + d8 * 8) =
        *reinterpret_cast<bf16x8*>(o);
}

// ---------------------------------------------------------------------------
// Fused persistent kernel, 2 independent batch-group chains (R10 structure).
// Group g = bid>>7 owns batches [g*32, g*32+32); block lb = bid&127 owns
// 8 L0-units + 4 L1-units. Phase p: PRE = mask prefetch + x_p*W0 (reg frags);
// wait = wave0 polls own group's 128 block-flags (1 u64/lane) + syncthreads;
// MAIN: prefetch ALL h1+h0 chunks upfront (single latency exposure), then
// h1 -> U1 (z1); h0 -> U0 (z0) + W1 (z1); dumps -> sync -> gates -> h stores
// -> sync (drains) -> tid0 flag -> out store (off critical path).
// All recurrent traffic agent-scope relaxed (sc0sc1, LLC-direct); no fences.
// ---------------------------------------------------------------------------
__global__ __launch_bounds__(256, 1)
void lstm_persistent(const __hip_bfloat16* __restrict__ xbf,
    const float* __restrict__ W0, const float* __restrict__ U0,
    const float* __restrict__ W1, const float* __restrict__ U1,
    const float* __restrict__ b0, const float* __restrict__ b1,
    const unsigned char* __restrict__ mask,
    __hip_bfloat16* h0ring, __hip_bfloat16* h1ring, float* __restrict__ out,
    int* flags)
{
    __shared__ __align__(16) unsigned char smem[LDS_BYTES];
    const int bid = blockIdx.x;
    const int g   = bid >> 7;          // batch group (0/1)
    const int lb  = bid & 127;         // block within group
    const int tid = threadIdx.x;
    const int w = tid >> 6, lane = tid & 63;
    const int mr = lane & 15, kgrp = lane >> 4;
    const int ub0 = lb * 8, ub1 = lb * 4;
    const int brow = g * 32;           // batch row base
    int* gflags = flags + g * 128;

    __hip_bfloat16* lu0h = (__hip_bfloat16*)(smem + LDS_U0);
    __hip_bfloat16* lw1h = (__hip_bfloat16*)(smem + LDS_W1);

    // ---- one-time LDS fill: U0 frags (cid 0..31, nf 0..1)
    for (int e = tid; e < 32 * 2 * 64; e += 256) {
        int ln  = e & 63;
        int nf  = (e >> 6) & 1;
        int cid = e >> 7;
        int nn  = nf * 16 + (ln & 15);
        int col = (nn >> 3) * 1024 + ub0 + (nn & 7);
        int kb  = cid * 32 + (ln >> 4) * 8;
        __hip_bfloat16* dst = lu0h + (size_t)e * 8;
        #pragma unroll
        for (int j = 0; j < 8; ++j)
            dst[j] = __float2bfloat16(U0[(size_t)(kb + j) * 4096 + col]);
    }
    // ---- one-time LDS fill: W1 frags (cid 0..31)
    for (int e = tid; e < 32 * 64; e += 256) {
        int ln  = e & 63;
        int cid = e >> 6;
        int nn  = ln & 15;
        int col = (nn >> 2) * 512 + ub1 + (nn & 3);
        int kb  = cid * 32 + (ln >> 4) * 8;
        __hip_bfloat16* dst = lw1h + (size_t)e * 8;
        #pragma unroll
        for (int j = 0; j < 8; ++j)
            dst[j] = __float2bfloat16(W1[(size_t)(kb + j) * 2048 + col]);
    }
    // ---- register frags: W0 (PRE) and U1, loop-invariant
    bf16x8 bw0[4][2];
    {
        int nn0 = lane & 15;
        #pragma unroll
        for (int c = 0; c < 4; ++c)
            #pragma unroll
            for (int nf = 0; nf < 2; ++nf) {
                int nn  = nf * 16 + nn0;
                int col = (nn >> 3) * 1024 + ub0 + (nn & 7);
                int kb  = (w * 4 + c) * 32 + kgrp * 8;
                union { short s[8]; bf16x8 v; } t;
                #pragma unroll
                for (int j = 0; j < 8; ++j)
                    t.s[j] = (short)bf16bits(W0[(size_t)(kb + j) * 4096 + col]);
                bw0[c][nf] = t.v;
            }
    }
    bf16x8 bu1[4];
    {
        int nn  = lane & 15;
        int col = (nn >> 2) * 512 + ub1 + (nn & 3);
        #pragma unroll
        for (int c = 0; c < 4; ++c) {
            int kb  = (w * 4 + c) * 32 + kgrp * 8;
            union { short s[8]; bf16x8 v; } t;
            #pragma unroll
            for (int j = 0; j < 8; ++j)
                t.s[j] = (short)bf16bits(U1[(size_t)(kb + j) * 2048 + col]);
            bu1[c] = t.v;
        }
    }

    // ---- per-thread gate state: bl = tid>>3 (32 batches), qp = tid&7
    const int bl = tid >> 3;
    const int qp = tid & 7;
    float h0reg[2] = {0.f, 0.f}, c0reg[2] = {0.f, 0.f}, br0[8];
    float h1reg[2] = {0.f, 0.f}, c1reg[2] = {0.f, 0.f}, br1[8];
    if (qp < 4) {
        #pragma unroll
        for (int i = 0; i < 2; ++i)
            #pragma unroll
            for (int gg = 0; gg < 4; ++gg)
                br0[i * 4 + gg] = b0[gg * H0_ + ub0 + qp * 2 + i];
    }
    if (qp < 2) {
        #pragma unroll
        for (int i = 0; i < 2; ++i)
            #pragma unroll
            for (int gg = 0; gg < 4; ++gg)
                br1[i * 4 + gg] = b1[gg * H1_ + ub1 + qp * 2 + i];
    }
    __syncthreads();

    float* zp0 = (float*)(smem + LDS_ZP0);
    float* zp1 = (float*)(smem + LDS_ZP1);
    const bf16x8* lu0 = (const bf16x8*)(smem + LDS_U0);
    const bf16x8* lw1 = (const bf16x8*)(smem + LDS_W1);

    #pragma unroll 1
    for (int p = 0; p <= T_; ++p) {
        const bool doL0 = (p < T_);
        const bool doL1 = (p >= 1);

        f32x4 acc0[2][2];
        f32x4 acc1[2];
        #pragma unroll
        for (int m = 0; m < 2; ++m) {
            f32x4 z = {0.f, 0.f, 0.f, 0.f};
            acc0[m][0] = z; acc0[m][1] = z; acc1[m] = z;
        }

        // ---- PRE: mask prefetch + z0 x-part (W0 reg frags; pre-wait)
        bool msk0 = false, msk1 = false;
        if (doL0) msk0 = mask[(brow + bl) * T_ + p] != 0;
        if (doL1) msk1 = mask[(brow + bl) * T_ + (p - 1)] != 0;
        if (doL0) {
            const __hip_bfloat16* xa = xbf + (size_t)p * (B_ * D_);
            #pragma unroll
            for (int c = 0; c < 4; ++c) {
                const int cid = w * 4 + c;
                #pragma unroll
                for (int m = 0; m < 2; ++m) {
                    bf16x8 af = *(const bf16x8*)(xa + (size_t)(brow + m * 16 + mr) * D_ + cid * 32 + kgrp * 8);
                    acc0[m][0] = __builtin_amdgcn_mfma_f32_16x16x32_bf16(af, bw0[c][0], acc0[m][0], 0, 0, 0);
                    acc0[m][1] = __builtin_amdgcn_mfma_f32_16x16x32_bf16(af, bw0[c][1], acc0[m][1], 0, 0, 0);
                }
            }
        }

        // ---- wait: wave0 polls own group's 128 block-flags (1 u64/lane), then barrier
        if (p > 0) {
            if (tid < 64) {
                const u64* f = (const u64*)gflags + tid;
                for (;;) {
                    u64 a = ald(f);
                    if (__all(((int)a >= p) && ((int)(a >> 32) >= p))) break;
                    __builtin_amdgcn_s_sleep(1);
                }
            }
            __syncthreads();
        }

        const __hip_bfloat16* h0r = h0ring + (size_t)((p + 1) & 1) * (B_ * H0_); // h0(p-1)
        const __hip_bfloat16* h1r = h1ring + (size_t)(p & 1) * (B_ * H1_);       // h1(p-2)

        // ---- prefetch ALL h1 + h0 chunks upfront (one latency exposure)
        u64 h1a[4][4];
        if (doL1) {
            #pragma unroll
            for (int c = 0; c < 4; ++c) {
                const __hip_bfloat16* src = h1r + w * 128 + c * 32 + kgrp * 8;
                #pragma unroll
                for (int m = 0; m < 2; ++m) {
                    const u64* hp = (const u64*)(src + (size_t)(brow + m * 16 + mr) * H1_);
                    h1a[c][2 * m]     = ald(hp);
                    h1a[c][2 * m + 1] = ald(hp + 1);
                }
            }
        }
        u64 h0a[8][4];
        #pragma unroll
        for (int c = 0; c < 8; ++c) {
            const __hip_bfloat16* src = h0r + w * 256 + c * 32 + kgrp * 8;
            #pragma unroll
            for (int m = 0; m < 2; ++m) {
                const u64* hp = (const u64*)(src + (size_t)(brow + m * 16 + mr) * H0_);
                h0a[c][2 * m]     = ald(hp);
                h0a[c][2 * m + 1] = ald(hp + 1);
            }
        }

        // ---- consume h1 (U1 reg frags -> z1)
        if (doL1) {
            #pragma unroll
            for (int c = 0; c < 4; ++c) {
                #pragma unroll
                for (int m = 0; m < 2; ++m) {
                    union { u64 u[2]; bf16x8 v; } au;
                    au.u[0] = h1a[c][2 * m]; au.u[1] = h1a[c][2 * m + 1];
                    acc1[m] = __builtin_amdgcn_mfma_f32_16x16x32_bf16(au.v, bu1[c], acc1[m], 0, 0, 0);
                }
            }
        }

        // ---- consume h0: shared A-frags feed U0 (z0) and W1 (z1)
        #pragma unroll
        for (int c = 0; c < 8; ++c) {
            const int wc = w * 8 + c;
            bf16x8 bu0a = lu0[(wc * 2 + 0) * 64 + lane];
            bf16x8 bu0b = lu0[(wc * 2 + 1) * 64 + lane];
            bf16x8 bw1  = lw1[wc * 64 + lane];
            #pragma unroll
            for (int m = 0; m < 2; ++m) {
                union { u64 u[2]; bf16x8 v; } au;
                au.u[0] = h0a[c][2 * m]; au.u[1] = h0a[c][2 * m + 1];
                if (doL0) {
                    acc0[m][0] = __builtin_amdgcn_mfma_f32_16x16x32_bf16(au.v, bu0a, acc0[m][0], 0, 0, 0);
                    acc0[m][1] = __builtin_amdgcn_mfma_f32_16x16x32_bf16(au.v, bu0b, acc0[m][1], 0, 0, 0);
                }
                if (doL1)
                    acc1[m] = __builtin_amdgcn_mfma_f32_16x16x32_bf16(au.v, bw1, acc1[m], 0, 0, 0);
            }
        }

        // ---- dumps to disjoint LDS, ONE sync
        if (doL0) {
            #pragma unroll
            for (int m = 0; m < 2; ++m)
                #pragma unroll
                for (int nf = 0; nf < 2; ++nf)
                    #pragma unroll
                    for (int r = 0; r < 4; ++r)
                        zp0[(w * 32 + m * 16 + kgrp * 4 + r) * ZROW0 + nf * 16 + mr] =
                            acc0[m][nf][r];
        }
        if (doL1) {
            #pragma unroll
            for (int m = 0; m < 2; ++m)
                #pragma unroll
                for (int r = 0; r < 4; ++r)
                    zp1[(w * 32 + m * 16 + kgrp * 4 + r) * ZROW1 + mr] = acc1[m][r];
        }
        __syncthreads();

        // ---- gates0 (qp<4) and gates1 (qp<2), then h stores
        if (doL0 && qp < 4) {
            #pragma unroll
            for (int i = 0; i < 2; ++i) {
                const int ul = qp * 2 + i;
                float z[4];
                #pragma unroll
                for (int gg = 0; gg < 4; ++gg) {
                    float s = br0[i * 4 + gg];
                    #pragma unroll
                    for (int wv = 0; wv < 4; ++wv)
                        s += zp0[(wv * 32 + bl) * ZROW0 + gg * 8 + ul];
                    z[gg] = s;
                }
                float ig = sigmf(z[0]), fg = sigmf(z[1]);
                float gv = tanhf(z[2]), og = sigmf(z[3]);
                float cn = fg * c0reg[i] + ig * gv;
                float hn = og * tanhf(cn);
                if (msk0) { c0reg[i] = cn; h0reg[i] = hn; }
            }
            __hip_bfloat16* h0w = h0ring + (size_t)(p & 1) * (B_ * H0_);
            union { unsigned short s[2]; unsigned u; } hv;
            hv.s[0] = bf16bits(h0reg[0]);
            hv.s[1] = bf16bits(h0reg[1]);
            __hip_atomic_store((unsigned*)&h0w[(size_t)(brow + bl) * H0_ + ub0 + qp * 2], hv.u,
                               __ATOMIC_RELAXED, __HIP_MEMORY_SCOPE_AGENT);
        }
        if (doL1 && qp < 2) {
            #pragma unroll
            for (int i = 0; i < 2; ++i) {
                const int ul = qp * 2 + i;
                float z[4];
                #pragma unroll
                for (int gg = 0; gg < 4; ++gg) {
                    float s = br1[i * 4 + gg];
                    #pragma unroll
                    for (int wv = 0; wv < 4; ++wv)
                        s += zp1[(wv * 32 + bl) * ZROW1 + gg * 4 + ul];
                    z[gg] = s;
                }
                float ig = sigmf(z[0]), fg = sigmf(z[1]);
                float gv = tanhf(z[2]), og = sigmf(z[3]);
                float cn = fg * c1reg[i] + ig * gv;
                float hn = og * tanhf(cn);
                if (msk1) { c1reg[i] = cn; h1reg[i] = hn; }
            }
            __hip_bfloat16* h1w = h1ring + (size_t)((p + 1) & 1) * (B_ * H1_); // slot (p-1)&1
            union { unsigned short s[2]; unsigned u; } hv;
            hv.s[0] = bf16bits(h1reg[0]);
            hv.s[1] = bf16bits(h1reg[1]);
            __hip_atomic_store((unsigned*)&h1w[(size_t)(brow + bl) * H1_ + ub1 + qp * 2], hv.u,
                               __ATOMIC_RELAXED, __HIP_MEMORY_SCOPE_AGENT);
        }

        // ---- drain h stores (per-wave vmcnt0 inside barrier), publish flag
        __syncthreads();
        if (p < T_ && tid == 0)
            __hip_atomic_store(gflags + lb, p + 1,
                               __ATOMIC_RELAXED, __HIP_MEMORY_SCOPE_AGENT);

        // ---- out store AFTER flag publish (nobody reads out)
        if (doL1 && qp < 2) {
            const int t1 = p - 1;
            float2 ov; ov.x = h1reg[0]; ov.y = h1reg[1];
            *reinterpret_cast<float2*>(&out[((size_t)(brow + bl) * T_ + t1) * H1_ + ub1 + qp * 2]) = ov;
        }
    }
}

// ---------------------------------------------------------------------------
extern "C" void kernel_launch(void* const* d_in, const int* in_sizes, int n_in,
                              void* d_out, int out_size, void* d_ws, size_t ws_size,
                              hipStream_t stream)
{
    const float* inputs = (const float*)d_in[0];
    const float* W0     = (const float*)d_in[1];
    const float* U0     = (const float*)d_in[2];
    const float* b0     = (const float*)d_in[3];
    const float* W1     = (const float*)d_in[4];
    const float* U1     = (const float*)d_in[5];
    const float* b1     = (const float*)d_in[6];
    float* out = (float*)d_out;

    // ws (bf16 elems): xbf 16,777,216 | h0ring 131,072 | h1ring 65,536
    //                  | mask 32,768 B | flags 1,024 B  (~32.4 MiB)
    __hip_bfloat16* xbf    = (__hip_bfloat16*)d_ws;
    __hip_bfloat16* h0ring = xbf + 16777216;
    __hip_bfloat16* h1ring = h0ring + 131072;
    unsigned char*  mask   = (unsigned char*)(h1ring + 65536);
    int* flags = (int*)(mask + 32768);

    hipMemsetAsync(h0ring, 0, (131072 + 65536) * sizeof(__hip_bfloat16), stream);
    hipMemsetAsync(flags, 0, NWORK * sizeof(int), stream);
    mask_kernel<<<(B_ * T_) / 4, 256, 0, stream>>>(inputs, mask);
    xbf_kernel<<<(B_ * T_ * D_ / 8) / 256, 256, 0, stream>>>(inputs, xbf);

    lstm_persistent<<<dim3(NWORK), dim3(256), 0, stream>>>(
        xbf, W0, U0, W1, U1, b0, b1, mask, h0ring, h1ring, out, flags);
}

// Round 14
// 4225.164 us; speedup vs baseline: 1.1820x; 1.1576x over previous
//
#include <hip/hip_runtime.h>
#include <hip/hip_bf16.h>
#include <cstdint>
#include <cstddef>

#define B_   64
#define T_   512
#define D_   512
#define H0_  1024
#define H1_  512
#define NWORK 256    // 2 groups x 128 blocks, 1 block/CU, plain launch

typedef __attribute__((ext_vector_type(8))) short bf16x8;
typedef __attribute__((ext_vector_type(4))) float f32x4;
typedef unsigned long long u64;

// LDS: U0 64KB @0 | W1 32KB @65536 | zp0 18,432B @98304 | zp1 10,240B @116736
#define LDS_U0  0
#define LDS_W1  65536
#define LDS_ZP0 98304
#define LDS_ZP1 116736
#define LDS_BYTES 126976
#define ZROW0 36
#define ZROW1 20

__device__ __forceinline__ float sigmf(float x) { return 1.0f / (1.0f + __expf(-x)); }
__device__ __forceinline__ unsigned short bf16bits(float x) {
    union { __hip_bfloat16 h; unsigned short s; } u; u.h = __float2bfloat16(x); return u.s;
}
__device__ __forceinline__ u64 ald(const void* p) {
    return __hip_atomic_load((const u64*)p, __ATOMIC_RELAXED, __HIP_MEMORY_SCOPE_AGENT);
}

// ---------------------------------------------------------------------------
__global__ void mask_kernel(const float* __restrict__ x, unsigned char* __restrict__ mask) {
    int row  = blockIdx.x * 4 + (threadIdx.x >> 6);
    int lane = threadIdx.x & 63;
    const float4* p = reinterpret_cast<const float4*>(x + (size_t)row * D_) + lane * 2;
    float4 a = p[0], b = p[1];
    bool nz = (a.x != 0.f) | (a.y != 0.f) | (a.z != 0.f) | (a.w != 0.f)
            | (b.x != 0.f) | (b.y != 0.f) | (b.z != 0.f) | (b.w != 0.f);
    int m = __any(nz);
    if (lane == 0) mask[row] = m ? 1 : 0;
}

__global__ void xbf_kernel(const float* __restrict__ in, __hip_bfloat16* __restrict__ xbf) {
    int i  = blockIdx.x * 256 + threadIdx.x;
    int d8 = i & 63;
    int row = i >> 6;
    int b = row >> 9, t = row & 511;
    const float* src = in + (size_t)row * D_ + d8 * 8;
    __hip_bfloat16 o[8];
    #pragma unroll
    for (int j = 0; j < 8; ++j) o[j] = __float2bfloat16(src[j]);
    *reinterpret_cast<bf16x8*>(xbf + ((size_t)t * B_ + b) * D_ + d8 * 8) =
        *reinterpret_cast<bf16x8*>(o);
}

// ---------------------------------------------------------------------------
// R10 structure + L2-amplified h broadcast.
// h WRITES: sc0sc1 (write-through to LLC, never dirty in L2) — R4/R5-proven.
// h READS: plain cached loads; coherence restored by ONE acquire fence
// (L1+L2 invalidate) per block per phase, issued by wave0 after its poll
// succeeds, before __syncthreads — the R3-proven read pattern. Each XCD's L2
// then fetches each h line once from LLC and serves its 32 resident blocks
// (~16x less LLC read traffic than sc0sc1-per-CU).
// ---------------------------------------------------------------------------
__global__ __launch_bounds__(256, 1)
void lstm_persistent(const __hip_bfloat16* __restrict__ xbf,
    const float* __restrict__ W0, const float* __restrict__ U0,
    const float* __restrict__ W1, const float* __restrict__ U1,
    const float* __restrict__ b0, const float* __restrict__ b1,
    const unsigned char* __restrict__ mask,
    __hip_bfloat16* h0ring, __hip_bfloat16* h1ring, float* __restrict__ out,
    int* flags)
{
    __shared__ __align__(16) unsigned char smem[LDS_BYTES];
    const int bid = blockIdx.x;
    const int g   = bid >> 7;          // batch group (0/1)
    const int lb  = bid & 127;         // block within group
    const int tid = threadIdx.x;
    const int w = tid >> 6, lane = tid & 63;
    const int mr = lane & 15, kgrp = lane >> 4;
    const int ub0 = lb * 8, ub1 = lb * 4;
    const int brow = g * 32;           // batch row base
    int* gflags = flags + g * 128;

    __hip_bfloat16* lu0h = (__hip_bfloat16*)(smem + LDS_U0);
    __hip_bfloat16* lw1h = (__hip_bfloat16*)(smem + LDS_W1);

    // ---- one-time LDS fill: U0 frags (cid 0..31, nf 0..1)
    for (int e = tid; e < 32 * 2 * 64; e += 256) {
        int ln  = e & 63;
        int nf  = (e >> 6) & 1;
        int cid = e >> 7;
        int nn  = nf * 16 + (ln & 15);
        int col = (nn >> 3) * 1024 + ub0 + (nn & 7);
        int kb  = cid * 32 + (ln >> 4) * 8;
        __hip_bfloat16* dst = lu0h + (size_t)e * 8;
        #pragma unroll
        for (int j = 0; j < 8; ++j)
            dst[j] = __float2bfloat16(U0[(size_t)(kb + j) * 4096 + col]);
    }
    // ---- one-time LDS fill: W1 frags (cid 0..31)
    for (int e = tid; e < 32 * 64; e += 256) {
        int ln  = e & 63;
        int cid = e >> 6;
        int nn  = ln & 15;
        int col = (nn >> 2) * 512 + ub1 + (nn & 3);
        int kb  = cid * 32 + (ln >> 4) * 8;
        __hip_bfloat16* dst = lw1h + (size_t)e * 8;
        #pragma unroll
        for (int j = 0; j < 8; ++j)
            dst[j] = __float2bfloat16(W1[(size_t)(kb + j) * 2048 + col]);
    }
    // ---- register frags: W0 (PRE) and U1, loop-invariant
    bf16x8 bw0[4][2];
    {
        int nn0 = lane & 15;
        #pragma unroll
        for (int c = 0; c < 4; ++c)
            #pragma unroll
            for (int nf = 0; nf < 2; ++nf) {
                int nn  = nf * 16 + nn0;
                int col = (nn >> 3) * 1024 + ub0 + (nn & 7);
                int kb  = (w * 4 + c) * 32 + kgrp * 8;
                union { short s[8]; bf16x8 v; } t;
                #pragma unroll
                for (int j = 0; j < 8; ++j)
                    t.s[j] = (short)bf16bits(W0[(size_t)(kb + j) * 4096 + col]);
                bw0[c][nf] = t.v;
            }
    }
    bf16x8 bu1[4];
    {
        int nn  = lane & 15;
        int col = (nn >> 2) * 512 + ub1 + (nn & 3);
        #pragma unroll
        for (int c = 0; c < 4; ++c) {
            int kb  = (w * 4 + c) * 32 + kgrp * 8;
            union { short s[8]; bf16x8 v; } t;
            #pragma unroll
            for (int j = 0; j < 8; ++j)
                t.s[j] = (short)bf16bits(U1[(size_t)(kb + j) * 2048 + col]);
            bu1[c] = t.v;
        }
    }

    // ---- per-thread gate state: bl = tid>>3 (32 batches), qp = tid&7
    const int bl = tid >> 3;
    const int qp = tid & 7;
    float h0reg[2] = {0.f, 0.f}, c0reg[2] = {0.f, 0.f}, br0[8];
    float h1reg[2] = {0.f, 0.f}, c1reg[2] = {0.f, 0.f}, br1[8];
    if (qp < 4) {
        #pragma unroll
        for (int i = 0; i < 2; ++i)
            #pragma unroll
            for (int gg = 0; gg < 4; ++gg)
                br0[i * 4 + gg] = b0[gg * H0_ + ub0 + qp * 2 + i];
    }
    if (qp < 2) {
        #pragma unroll
        for (int i = 0; i < 2; ++i)
            #pragma unroll
            for (int gg = 0; gg < 4; ++gg)
                br1[i * 4 + gg] = b1[gg * H1_ + ub1 + qp * 2 + i];
    }
    __syncthreads();

    float* zp0 = (float*)(smem + LDS_ZP0);
    float* zp1 = (float*)(smem + LDS_ZP1);
    const bf16x8* lu0 = (const bf16x8*)(smem + LDS_U0);
    const bf16x8* lw1 = (const bf16x8*)(smem + LDS_W1);

    #pragma unroll 1
    for (int p = 0; p <= T_; ++p) {
        const bool doL0 = (p < T_);
        const bool doL1 = (p >= 1);

        f32x4 acc0[2][2];
        f32x4 acc1[2];
        #pragma unroll
        for (int m = 0; m < 2; ++m) {
            f32x4 z = {0.f, 0.f, 0.f, 0.f};
            acc0[m][0] = z; acc0[m][1] = z; acc1[m] = z;
        }

        // ---- PRE: z0 x-part (W0 reg frags; pre-wait)
        if (doL0) {
            const __hip_bfloat16* xa = xbf + (size_t)p * (B_ * D_);
            #pragma unroll
            for (int c = 0; c < 4; ++c) {
                const int cid = w * 4 + c;
                #pragma unroll
                for (int m = 0; m < 2; ++m) {
                    bf16x8 af = *(const bf16x8*)(xa + (size_t)(brow + m * 16 + mr) * D_ + cid * 32 + kgrp * 8);
                    acc0[m][0] = __builtin_amdgcn_mfma_f32_16x16x32_bf16(af, bw0[c][0], acc0[m][0], 0, 0, 0);
                    acc0[m][1] = __builtin_amdgcn_mfma_f32_16x16x32_bf16(af, bw0[c][1], acc0[m][1], 0, 0, 0);
                }
            }
        }

        // ---- wait: wave0 polls own group's 128 block-flags, acquire fence
        //      (L1+L2 inv; R3-proven leader pattern), then barrier
        if (p > 0) {
            if (tid < 64) {
                const u64* f = (const u64*)gflags + tid;
                for (;;) {
                    u64 a = ald(f);
                    if (__all(((int)a >= p) && ((int)(a >> 32) >= p))) break;
                    __builtin_amdgcn_s_sleep(1);
                }
                __builtin_amdgcn_fence(__ATOMIC_ACQUIRE, "agent");
            }
            __syncthreads();
        }

        const __hip_bfloat16* h0r = h0ring + (size_t)((p + 1) & 1) * (B_ * H0_); // h0(p-1)
        const __hip_bfloat16* h1r = h1ring + (size_t)(p & 1) * (B_ * H1_);       // h1(p-2)

        // ---- h1 loads (plain cached, L2-amplified; issued first)
        bf16x8 h1a[4][2];
        if (doL1) {
            #pragma unroll
            for (int c = 0; c < 4; ++c) {
                const __hip_bfloat16* src = h1r + w * 128 + c * 32 + kgrp * 8;
                #pragma unroll
                for (int m = 0; m < 2; ++m)
                    h1a[c][m] = *(const bf16x8*)(src + (size_t)(brow + m * 16 + mr) * H1_);
            }
        }

        // ---- h0 pipeline: prologue 4 chunks (plain cached loads)
        bf16x8 areg[4][2];
        auto ldc = [&](int c, bf16x8* dst) {
            const __hip_bfloat16* src = h0r + w * 256 + c * 32 + kgrp * 8;
            #pragma unroll
            for (int m = 0; m < 2; ++m)
                dst[m] = *(const bf16x8*)(src + (size_t)(brow + m * 16 + mr) * H0_);
        };
        #pragma unroll
        for (int c = 0; c < 4; ++c) ldc(c, areg[c]);

        // ---- consume h1 (U1 reg frags -> z1)
        if (doL1) {
            #pragma unroll
            for (int c = 0; c < 4; ++c) {
                #pragma unroll
                for (int m = 0; m < 2; ++m)
                    acc1[m] = __builtin_amdgcn_mfma_f32_16x16x32_bf16(h1a[c][m], bu1[c], acc1[m], 0, 0, 0);
            }
        }

        // ---- h0 loop: shared A-frags feed U0 (z0) and W1 (z1)
        #pragma unroll
        for (int c = 0; c < 8; ++c) {
            bf16x8 cur[2];
            cur[0] = areg[c & 3][0];
            cur[1] = areg[c & 3][1];
            if (c + 4 < 8) ldc(c + 4, areg[c & 3]);
            const int wc = w * 8 + c;
            bf16x8 bu0a = lu0[(wc * 2 + 0) * 64 + lane];
            bf16x8 bu0b = lu0[(wc * 2 + 1) * 64 + lane];
            bf16x8 bw1  = lw1[wc * 64 + lane];
            #pragma unroll
            for (int m = 0; m < 2; ++m) {
                if (doL0) {
                    acc0[m][0] = __builtin_amdgcn_mfma_f32_16x16x32_bf16(cur[m], bu0a, acc0[m][0], 0, 0, 0);
                    acc0[m][1] = __builtin_amdgcn_mfma_f32_16x16x32_bf16(cur[m], bu0b, acc0[m][1], 0, 0, 0);
                }
                if (doL1)
                    acc1[m] = __builtin_amdgcn_mfma_f32_16x16x32_bf16(cur[m], bw1, acc1[m], 0, 0, 0);
            }
        }

        // ---- dumps to disjoint LDS, ONE sync
        if (doL0) {
            #pragma unroll
            for (int m = 0; m < 2; ++m)
                #pragma unroll
                for (int nf = 0; nf < 2; ++nf)
                    #pragma unroll
                    for (int r = 0; r < 4; ++r)
                        zp0[(w * 32 + m * 16 + kgrp * 4 + r) * ZROW0 + nf * 16 + mr] =
                            acc0[m][nf][r];
        }
        if (doL1) {
            #pragma unroll
            for (int m = 0; m < 2; ++m)
                #pragma unroll
                for (int r = 0; r < 4; ++r)
                    zp1[(w * 32 + m * 16 + kgrp * 4 + r) * ZROW1 + mr] = acc1[m][r];
        }
        __syncthreads();

        // ---- gates0 (qp<4) and gates1 (qp<2), then h stores (sc0sc1)
        if (doL0 && qp < 4) {
            const bool msk = mask[(brow + bl) * T_ + p] != 0;
            #pragma unroll
            for (int i = 0; i < 2; ++i) {
                const int ul = qp * 2 + i;
                float z[4];
                #pragma unroll
                for (int gg = 0; gg < 4; ++gg) {
                    float s = br0[i * 4 + gg];
                    #pragma unroll
                    for (int wv = 0; wv < 4; ++wv)
                        s += zp0[(wv * 32 + bl) * ZROW0 + gg * 8 + ul];
                    z[gg] = s;
                }
                float ig = sigmf(z[0]), fg = sigmf(z[1]);
                float gv = tanhf(z[2]), og = sigmf(z[3]);
                float cn = fg * c0reg[i] + ig * gv;
                float hn = og * tanhf(cn);
                if (msk) { c0reg[i] = cn; h0reg[i] = hn; }
            }
            __hip_bfloat16* h0w = h0ring + (size_t)(p & 1) * (B_ * H0_);
            union { unsigned short s[2]; unsigned u; } hv;
            hv.s[0] = bf16bits(h0reg[0]);
            hv.s[1] = bf16bits(h0reg[1]);
            __hip_atomic_store((unsigned*)&h0w[(size_t)(brow + bl) * H0_ + ub0 + qp * 2], hv.u,
                               __ATOMIC_RELAXED, __HIP_MEMORY_SCOPE_AGENT);
        }
        if (doL1 && qp < 2) {
            const int t1 = p - 1;
            const bool msk = mask[(brow + bl) * T_ + t1] != 0;
            #pragma unroll
            for (int i = 0; i < 2; ++i) {
                const int ul = qp * 2 + i;
                float z[4];
                #pragma unroll
                for (int gg = 0; gg < 4; ++gg) {
                    float s = br1[i * 4 + gg];
                    #pragma unroll
                    for (int wv = 0; wv < 4; ++wv)
                        s += zp1[(wv * 32 + bl) * ZROW1 + gg * 4 + ul];
                    z[gg] = s;
                }
                float ig = sigmf(z[0]), fg = sigmf(z[1]);
                float gv = tanhf(z[2]), og = sigmf(z[3]);
                float cn = fg * c1reg[i] + ig * gv;
                float hn = og * tanhf(cn);
                if (msk) { c1reg[i] = cn; h1reg[i] = hn; }
            }
            __hip_bfloat16* h1w = h1ring + (size_t)((p + 1) & 1) * (B_ * H1_); // slot (p-1)&1
            union { unsigned short s[2]; unsigned u; } hv;
            hv.s[0] = bf16bits(h1reg[0]);
            hv.s[1] = bf16bits(h1reg[1]);
            __hip_atomic_store((unsigned*)&h1w[(size_t)(brow + bl) * H1_ + ub1 + qp * 2], hv.u,
                               __ATOMIC_RELAXED, __HIP_MEMORY_SCOPE_AGENT);
        }

        // ---- drain h stores (per-wave vmcnt0 inside barrier), publish flag
        __syncthreads();
        if (p < T_ && tid == 0)
            __hip_atomic_store(gflags + lb, p + 1,
                               __ATOMIC_RELAXED, __HIP_MEMORY_SCOPE_AGENT);

        // ---- out store AFTER flag publish (nobody reads out)
        if (doL1 && qp < 2) {
            const int t1 = p - 1;
            float2 ov; ov.x = h1reg[0]; ov.y = h1reg[1];
            *reinterpret_cast<float2*>(&out[((size_t)(brow + bl) * T_ + t1) * H1_ + ub1 + qp * 2]) = ov;
        }
    }
}

// ---------------------------------------------------------------------------
extern "C" void kernel_launch(void* const* d_in, const int* in_sizes, int n_in,
                              void* d_out, int out_size, void* d_ws, size_t ws_size,
                              hipStream_t stream)
{
    const float* inputs = (const float*)d_in[0];
    const float* W0     = (const float*)d_in[1];
    const float* U0     = (const float*)d_in[2];
    const float* b0     = (const float*)d_in[3];
    const float* W1     = (const float*)d_in[4];
    const float* U1     = (const float*)d_in[5];
    const float* b1     = (const float*)d_in[6];
    float* out = (float*)d_out;

    // ws (bf16 elems): xbf 16,777,216 | h0ring 131,072 | h1ring 65,536
    //                  | mask 32,768 B | flags 1,024 B  (~32.4 MiB)
    __hip_bfloat16* xbf    = (__hip_bfloat16*)d_ws;
    __hip_bfloat16* h0ring = xbf + 16777216;
    __hip_bfloat16* h1ring = h0ring + 131072;
    unsigned char*  mask   = (unsigned char*)(h1ring + 65536);
    int* flags = (int*)(mask + 32768);

    hipMemsetAsync(h0ring, 0, (131072 + 65536) * sizeof(__hip_bfloat16), stream);
    hipMemsetAsync(flags, 0, NWORK * sizeof(int), stream);
    mask_kernel<<<(B_ * T_) / 4, 256, 0, stream>>>(inputs, mask);
    xbf_kernel<<<(B_ * T_ * D_ / 8) / 256, 256, 0, stream>>>(inputs, xbf);

    lstm_persistent<<<dim3(NWORK), dim3(256), 0, stream>>>(
        xbf, W0, U0, W1, U1, b0, b1, mask, h0ring, h1ring, out, flags);
}